// Round 8
// baseline (493.198 us; speedup 1.0000x reference)
//
#include <hip/hip_runtime.h>
#include <hip/hip_bf16.h>
#include <cstdint>
#include <cstddef>
#include <cmath>

typedef __bf16 bf16_t;
typedef __bf16 bf16x8 __attribute__((ext_vector_type(8)));
typedef __bf16 bf16x4v __attribute__((ext_vector_type(4)));
typedef float f32x16 __attribute__((ext_vector_type(16)));

#define B_SZ 4
#define L_SZ 4096
#define H_SZ 2048
#define R_SZ 256
// exp(S) with S = acc/16  ->  2^(acc * log2(e)/16)
#define EXP_SC 0.090168440f
// E pair-panel geometry: pair P holds 256 rows x (P+1)*256 cols bf16
#define E2_ELEMS 8912896L   // 65536 * (1+2+...+16) elements per batch
#define E2_BYTES 17825792L

// async global->LDS, 16B per lane. LDS dest must be wave-uniform base (+lane*16 by HW).
#define GLDS16(gaddr, laddr)                                                    \
  __builtin_amdgcn_global_load_lds(                                             \
      (const __attribute__((address_space(1))) void*)(gaddr),                   \
      (__attribute__((address_space(3))) void*)(laddr), 16, 0, 0)

__device__ __forceinline__ f32x16 mfma32(bf16x8 a, bf16x8 b, f32x16 c) {
  return __builtin_amdgcn_mfma_f32_32x32x16_bf16(a, b, c, 0, 0, 0);
}

__device__ __forceinline__ float rsum32(float v) {
  v += __shfl_xor(v, 1, 32);
  v += __shfl_xor(v, 2, 32);
  v += __shfl_xor(v, 4, 32);
  v += __shfl_xor(v, 8, 32);
  v += __shfl_xor(v, 16, 32);
  return v;
}

// ---------------- fused conversion kernel ----------------
__global__ void conv_kernel(const float* __restrict__ x, const float* __restrict__ Ws,
                            const float* __restrict__ Wa, const float* __restrict__ Wo,
                            bf16_t* __restrict__ xb, bf16_t* __restrict__ Wst,
                            bf16_t* __restrict__ Wat, bf16_t* __restrict__ Wob,
                            float* __restrict__ lsum) {
  const int tid = blockIdx.x * blockDim.x + threadIdx.x;
  const int stride = gridDim.x * blockDim.x;
  const int n4 = B_SZ * L_SZ * H_SZ / 4;
  for (int i = tid; i < n4; i += stride) {
    float4 v = reinterpret_cast<const float4*>(x)[i];
    bf16x4v o;
    o[0] = (bf16_t)v.x; o[1] = (bf16_t)v.y; o[2] = (bf16_t)v.z; o[3] = (bf16_t)v.w;
    reinterpret_cast<bf16x4v*>(xb)[i] = o;
  }
  // transpose [H, R] -> [R, H]
  for (int idx = tid; idx < R_SZ * H_SZ; idx += stride) {
    const int rr = idx >> 11;
    const int h  = idx & (H_SZ - 1);
    Wst[idx] = (bf16_t)Ws[h * R_SZ + rr];
    Wat[idx] = (bf16_t)Wa[h * R_SZ + rr];
  }
  for (int idx = tid; idx < H_SZ * H_SZ; idx += stride) {
    Wob[idx] = (bf16_t)Wo[idx];
  }
  for (int idx = tid; idx < B_SZ * L_SZ; idx += stride) lsum[idx] = 0.0f;
}

// ================= 256x256 GEMM core — 32x32x16 MFMA, 2-barrier overlapped tile (R8) ========
// C[m,n] = sum_k A[m,k] B[n,k], A row-major [256 rows from Ag], B row-major [256 rows from Bg],
// K = NT*64 (NT even, >= 4). 512 threads = 8 waves (2M x 4N). LDS 128 KiB dynamic.
// Each wave owns 8x 32x32 C-blocks: rows rb(am)=((am>>1)*4+(am&1)*2+wr)*32, am=0..3;
// cols an*128 + wc*32, an=0..1. MFMA v_mfma_f32_32x32x16_bf16 (m119: 2495 TF vs 2176 for 16x16).
// A-frag: row=lane&31, k=8*(lane>>5)+i (16B/lane contiguous); B-frag mirrored; C/D per verified
// m74/m101 mapping col=lane&31, row=(reg&3)+8*(reg>>2)+4*(lane>>5).
// LDS: A region [0,64K): buf(32K) x half(16K); B region [64K,128K). Linear [128 rows][128 B] per
// half-slot, swizzle realized by pre-swizzled global source; reads XOR the same mask.
// Sync design: 2 barriers per K-tile (region1 covers MH0 + stages T+1 h1-halves + issues A1
// reads with counted lgkmcnt(8); region2 covers MH1 + stages T+2 h0-halves + vmcnt(4)).

#define G8_STG(P, REGION, BUFOFF, HALF)                                        \
  GLDS16((P)[0], lds + (REGION) + (BUFOFF) + (HALF)*16384 + ldst0);            \
  GLDS16((P)[1], lds + (REGION) + (BUFOFF) + (HALF)*16384 + ldst1);            \
  (P)[0] += 128; (P)[1] += 128;

#define G32_LDA(MH, BO) {                                                      \
  const char* ap_ = lds + (BO) + (MH)*16384 + aRowOff;                         \
  fa[0][0] = *(const bf16x8*)(ap_ + kb0);                                      \
  fa[0][1] = *(const bf16x8*)(ap_ + kb1);                                      \
  fa[0][2] = *(const bf16x8*)(ap_ + kb2);                                      \
  fa[0][3] = *(const bf16x8*)(ap_ + kb3);                                      \
  fa[1][0] = *(const bf16x8*)(ap_ + 8192 + kb0);                               \
  fa[1][1] = *(const bf16x8*)(ap_ + 8192 + kb1);                               \
  fa[1][2] = *(const bf16x8*)(ap_ + 8192 + kb2);                               \
  fa[1][3] = *(const bf16x8*)(ap_ + 8192 + kb3); }

#define G32_LDB(NH, BO) {                                                      \
  const char* bp_ = lds + 65536 + (BO) + (NH)*16384 + bRowOff;                 \
  fb[NH][0] = *(const bf16x8*)(bp_ + kb0);                                     \
  fb[NH][1] = *(const bf16x8*)(bp_ + kb1);                                     \
  fb[NH][2] = *(const bf16x8*)(bp_ + kb2);                                     \
  fb[NH][3] = *(const bf16x8*)(bp_ + kb3); }

#define G32_MM(MH, NH)                                                         \
  acc[(MH)*2+0][NH] = mfma32(fa[0][0], fb[NH][0], acc[(MH)*2+0][NH]);          \
  acc[(MH)*2+1][NH] = mfma32(fa[1][0], fb[NH][0], acc[(MH)*2+1][NH]);          \
  acc[(MH)*2+0][NH] = mfma32(fa[0][1], fb[NH][1], acc[(MH)*2+0][NH]);          \
  acc[(MH)*2+1][NH] = mfma32(fa[1][1], fb[NH][1], acc[(MH)*2+1][NH]);          \
  acc[(MH)*2+0][NH] = mfma32(fa[0][2], fb[NH][2], acc[(MH)*2+0][NH]);          \
  acc[(MH)*2+1][NH] = mfma32(fa[1][2], fb[NH][2], acc[(MH)*2+1][NH]);          \
  acc[(MH)*2+0][NH] = mfma32(fa[0][3], fb[NH][3], acc[(MH)*2+0][NH]);          \
  acc[(MH)*2+1][NH] = mfma32(fa[1][3], fb[NH][3], acc[(MH)*2+1][NH])

// region 1: reads A-h0 + B-h0 + B-h1; stages (T+1) h1-halves; MFMA MH0; A-h1 reads; lgkmcnt(8).
#define G8_REGION1(BO, S1A, S1B)                                               \
  G32_LDA(0, BO);                                                              \
  G32_LDB(0, BO);                                                              \
  G32_LDB(1, BO);                                                              \
  S1A; S1B;                                                                    \
  __builtin_amdgcn_s_setprio(1);                                               \
  G32_MM(0, 0);                                                                \
  G32_MM(0, 1);                                                                \
  __builtin_amdgcn_s_setprio(0);                                               \
  G32_LDA(1, BO);                                                              \
  asm volatile("s_waitcnt lgkmcnt(8)" ::: "memory");                           \
  __builtin_amdgcn_sched_barrier(0);                                           \
  __builtin_amdgcn_s_barrier();

// region 2: stages (T+2) h0-halves; MFMA MH1; drain lgkm; counted vmcnt; barrier.
#define G8_REGION2(S2A, S2B, WAITS)                                            \
  S2A; S2B;                                                                    \
  __builtin_amdgcn_s_setprio(1);                                               \
  G32_MM(1, 0);                                                                \
  G32_MM(1, 1);                                                                \
  __builtin_amdgcn_s_setprio(0);                                               \
  asm volatile("s_waitcnt lgkmcnt(0)" ::: "memory");                           \
  WAITS;                                                                       \
  __builtin_amdgcn_sched_barrier(0);                                           \
  __builtin_amdgcn_s_barrier();

__device__ __forceinline__ void gemm8_core(
    const char* Ag, const char* Bg, long aRowB, long bRowB, int NT,
    char* lds, f32x16 (&acc)[4][2])
{
  const int t = threadIdx.x;
  const int l = t & 63;
  const int wid = t >> 6;
  const int wr = wid >> 2;
  const int wc = wid & 3;
  const int l31 = l & 31;
  const int l5 = l >> 5;
  const int swz = (l & 7) << 4;
  const int kb0 = (0 * 32 + l5 * 16) ^ swz;
  const int kb1 = (1 * 32 + l5 * 16) ^ swz;
  const int kb2 = (2 * 32 + l5 * 16) ^ swz;
  const int kb3 = (3 * 32 + l5 * 16) ^ swz;
  const int aRowOff = (wr * 32 + l31) * 128;
  const int bRowOff = (wc * 32 + l31) * 128;
  // staging: per-thread, 2 x 16B per half-tile; d = t*16 + i*8192 covers [0,16K) linear
  const int d0 = t * 16, d1 = t * 16 + 8192;
  const int r0 = d0 >> 7, r1 = d1 >> 7;
  const int s0 = (d0 & 127) ^ ((r0 & 7) << 4);
  const int s1 = (d1 & 127) ^ ((r1 & 7) << 4);
  const char* pA0[2] = { Ag + (long)r0 * aRowB + s0, Ag + (long)r1 * aRowB + s1 };
  const char* pA1[2] = { Ag + (long)(128 + r0) * aRowB + s0, Ag + (long)(128 + r1) * aRowB + s1 };
  const char* pB0[2] = { Bg + (long)r0 * bRowB + s0, Bg + (long)r1 * bRowB + s1 };
  const char* pB1[2] = { Bg + (long)(128 + r0) * bRowB + s0, Bg + (long)(128 + r1) * bRowB + s1 };
  const int ldst0 = wid * 1024, ldst1 = wid * 1024 + 8192;
  bf16x8 fa[2][4], fb[2][4];

  // prologue: stage tile0 (A0,B0,A1,B1) + tile1 (A0,B0); wait tile0; barrier
  G8_STG(pA0, 0, 0, 0);
  G8_STG(pB0, 65536, 0, 0);
  G8_STG(pA1, 0, 0, 1);
  G8_STG(pB1, 65536, 0, 1);
  G8_STG(pA0, 0, 32768, 0);
  G8_STG(pB0, 65536, 32768, 0);
  asm volatile("s_waitcnt vmcnt(4)" ::: "memory");
  __builtin_amdgcn_sched_barrier(0);
  __builtin_amdgcn_s_barrier();

  int bufOff = 0;
  for (int T = 0; T < NT - 2; ++T) {
    const int ob = bufOff ^ 32768;
    G8_REGION1(bufOff, G8_STG(pA1, 0, ob, 1), G8_STG(pB1, 65536, ob, 1));
    G8_REGION2(G8_STG(pA0, 0, bufOff, 0), G8_STG(pB0, 65536, bufOff, 0),
               asm volatile("s_waitcnt vmcnt(4)" ::: "memory"));
    bufOff ^= 32768;
  }
  // T = NT-2: stage only (NT-1).A1/B1; drain at region 2
  {
    const int ob = bufOff ^ 32768;
    G8_REGION1(bufOff, G8_STG(pA1, 0, ob, 1), G8_STG(pB1, 65536, ob, 1));
    G8_REGION2(, , asm volatile("s_waitcnt vmcnt(0)" ::: "memory"));
    bufOff ^= 32768;
  }
  // T = NT-1: compute only
  {
    G8_REGION1(bufOff, , );
    G8_REGION2(, , );
  }
}

// C-block row base within the 256-row tile for sub-block am (0..3) of wave-row wr.
__device__ __forceinline__ int rb32(int am, int wr) {
  return ((am >> 1) * 4 + (am & 1) * 2 + wr) * 32;
}

// ---------------- fused V'+QK GEMM kernel ----------------
// Flat grid 640 blocks. f < 128: QK projection. f >= 128: V' GEMM with XCD-chunked swizzle.
__global__ __launch_bounds__(512) void vq8_kernel(
    const bf16_t* __restrict__ Wob, const bf16_t* __restrict__ xb, bf16_t* __restrict__ VT,
    const bf16_t* __restrict__ Wst, const bf16_t* __restrict__ Wat,
    bf16_t* __restrict__ Qb, bf16_t* __restrict__ Kb)
{
  extern __shared__ char lds[];
  const int f = blockIdx.x;
  const int t = threadIdx.x, l = t & 63, wid = t >> 6;
  const int wr = wid >> 2, wc = wid & 3, l31 = l & 31, l5 = l >> 5;
  long mBase, nBase;
  const char* Ag;
  const char* Bg;
  bf16_t* Cp;
  long ldc;
  if (f < 128) {
    const int proj = f >> 6;
    mBase = (long)(f & 63) * 256;
    nBase = 0;
    Ag = (const char*)xb + mBase * (H_SZ * 2);
    Bg = (const char*)(proj ? Wat : Wst);
    Cp = proj ? Kb : Qb;
    ldc = R_SZ;
  } else {
    const int g = f - 128;                    // 0..511
    const int lg = (g & 7) * 64 + (g >> 3);   // bijective (512 = 8*64)
    const int xo = lg & 7;
    const int yj = (lg >> 3) & 15;
    const int b  = lg >> 7;
    mBase = (long)xo * 256;                   // o
    nBase = (long)yj * 256;                   // j
    Ag = (const char*)Wob + mBase * (H_SZ * 2);
    Bg = (const char*)xb + ((long)b * L_SZ + nBase) * (H_SZ * 2);
    Cp = VT + (long)b * H_SZ * L_SZ;
    ldc = L_SZ;
  }
  f32x16 acc[4][2] = {};
  gemm8_core(Ag, Bg, H_SZ * 2, H_SZ * 2, H_SZ / 64, lds, acc);
#pragma unroll
  for (int am = 0; am < 4; ++am) {
    const int rbase = rb32(am, wr);
#pragma unroll
    for (int an = 0; an < 2; ++an) {
      const long col = nBase + an * 128 + wc * 32 + l31;
#pragma unroll
      for (int q = 0; q < 16; ++q) {
        const long row = mBase + rbase + (q & 3) + 8 * (q >> 2) + 4 * l5;
        Cp[row * ldc + col] = (bf16_t)acc[am][an][q];
      }
    }
  }
}

// ---------------- pass 1: E = exp(Q K^T / 16) (causal) pair-panels + row sums ----------------
// Flat grid 544 (= 4 b x 136 triangular tiles), XCD-chunked so same-Q-panel blocks share an L2.
__global__ __launch_bounds__(512) void ep8_kernel(
    const bf16_t* __restrict__ Qb, const bf16_t* __restrict__ Kb,
    bf16_t* __restrict__ E, float* __restrict__ lsum)
{
  extern __shared__ char lds[];
  const int f = blockIdx.x;                  // 0..543
  const int lg = (f & 7) * 68 + (f >> 3);    // bijective (544 = 8*68)
  const int b = lg / 136;
  const int t136 = lg - b * 136;
  int P = (int)((sqrtf((float)(8 * t136 + 1)) - 1.0f) * 0.5f);
  while ((P + 1) * (P + 2) / 2 <= t136) ++P;
  while (P * (P + 1) / 2 > t136) --P;
  const int Jp = t136 - P * (P + 1) / 2;     // 0..P

  f32x16 acc[4][2] = {};
  gemm8_core((const char*)Qb + ((long)b * L_SZ + P * 256) * (R_SZ * 2),
             (const char*)Kb + ((long)b * L_SZ + Jp * 256) * (R_SZ * 2),
             R_SZ * 2, R_SZ * 2, R_SZ / 64, lds, acc);
  const int t = threadIdx.x, l = t & 63, wid = t >> 6;
  const int wr = wid >> 2, wc = wid & 3, l31 = l & 31, l5 = l >> 5;
  bf16_t* Ep = E + (long)b * E2_ELEMS + 32768L * P * (P + 1);
  const long ldaE = (long)(P + 1) * 256;
  float* lp = lsum + (long)b * L_SZ + P * 256;
  const bool diag = (Jp == P);
#pragma unroll
  for (int am = 0; am < 4; ++am) {
    const int rbase = rb32(am, wr);
#pragma unroll
    for (int q = 0; q < 16; ++q) {
      const int rowi = rbase + (q & 3) + 8 * (q >> 2) + 4 * l5;
      float s = 0.0f;
#pragma unroll
      for (int an = 0; an < 2; ++an) {
        const int coli = an * 128 + wc * 32 + l31;
        float p = exp2f(acc[am][an][q] * EXP_SC);
        if (diag && coli > rowi) p = 0.0f;   // jj > ii within the diagonal 256-tile
        Ep[(long)rowi * ldaE + Jp * 256 + coli] = (bf16_t)p;
        s += p;
      }
      s = rsum32(s);
      if (l31 == 0) atomicAdd(lp + rowi, s);
    }
  }
}

// ---------------- pass 2: out = (E @ V'^T) / l + bo, paired tiles for balance ----------------
// Flat grid 256; XCD-chunked swizzle: each XCD gets 4 pr-pairs x 8 j-slices, one b.
__global__ __launch_bounds__(512) void pv8_kernel(
    const bf16_t* __restrict__ E, const bf16_t* __restrict__ VT,
    const float* __restrict__ lsum, const float* __restrict__ bo,
    float* __restrict__ out)
{
  extern __shared__ char lds[];
  const int f = blockIdx.x;                 // 0..255
  const int lg = (f & 7) * 32 + (f >> 3);   // bijective (256 = 8*32)
  const int yj = lg & 7;
  const int pr = (lg >> 3) & 7;
  const int b  = lg >> 6;
  const int nBase = yj * 256;
  const int t = threadIdx.x, l = t & 63, wid = t >> 6;
  const int wr = wid >> 2, wc = wid & 3, l31 = l & 31, l5 = l >> 5;

#pragma unroll
  for (int s = 0; s < 2; ++s) {
    const int mt = s ? pr : (15 - pr);
    f32x16 acc[4][2] = {};
    const char* Ag = (const char*)E + (long)b * E2_BYTES + 65536L * mt * (mt + 1);
    const char* Bg = (const char*)VT + ((long)b * H_SZ + nBase) * (L_SZ * 2);
    gemm8_core(Ag, Bg, (long)(mt + 1) * 512, L_SZ * 2, (mt + 1) * 4, lds, acc);
#pragma unroll
    for (int am = 0; am < 4; ++am) {
      const int rbase = rb32(am, wr);
#pragma unroll
      for (int an = 0; an < 2; ++an) {
        const int colG = nBase + an * 128 + wc * 32 + l31;
        const float bias = bo[colG];
#pragma unroll
        for (int q = 0; q < 16; ++q) {
          const long rowG = (long)b * L_SZ + mt * 256 + rbase + (q & 3) + 8 * (q >> 2) + 4 * l5;
          out[rowG * H_SZ + colG] = acc[am][an][q] / lsum[rowG] + bias;
        }
      }
    }
  }
}

extern "C" void kernel_launch(void* const* d_in, const int* in_sizes, int n_in,
                              void* d_out, int out_size, void* d_ws, size_t ws_size,
                              hipStream_t stream) {
  const float* x  = (const float*)d_in[0];
  const float* Ws = (const float*)d_in[1];
  const float* Wa = (const float*)d_in[2];
  const float* Wo = (const float*)d_in[3];
  const float* bo = (const float*)d_in[4];
  float* out = (float*)d_out;

  char* ws = (char*)d_ws;
  // layout (bytes):
  //   [0, 64M)        xb   (dead after V'/QK)  -- aliased by E pair-panels
  //   [64M, 65M)      Wst  (dead after QK)     -- aliased by E
  //   [65M, 66M)      Wat  (dead after QK)     -- aliased by E
  //   [66M, 74M)      Wob  (dead after V')     -- head aliased by E (E = 71.3MB < 74M)
  //   [74M, 82M)      Qb
  //   [82M, 90M)      Kb
  //   [90M, 154M)     VT
  //   [154M, +64K)    lsum
  bf16_t* xb  = (bf16_t*)(ws + 0);
  bf16_t* Wst = (bf16_t*)(ws + 67108864);
  bf16_t* Wat = (bf16_t*)(ws + 68157440);
  bf16_t* Wob = (bf16_t*)(ws + 69206016);
  bf16_t* Qb  = (bf16_t*)(ws + 77594624);
  bf16_t* Kb  = (bf16_t*)(ws + 85983232);
  bf16_t* VT  = (bf16_t*)(ws + 94371840);
  float*  lsum = (float*)(ws + 161480704);
  bf16_t* E   = (bf16_t*)(ws + 0);

  hipFuncSetAttribute((const void*)vq8_kernel, hipFuncAttributeMaxDynamicSharedMemorySize, 131072);
  hipFuncSetAttribute((const void*)ep8_kernel, hipFuncAttributeMaxDynamicSharedMemorySize, 131072);
  hipFuncSetAttribute((const void*)pv8_kernel, hipFuncAttributeMaxDynamicSharedMemorySize, 131072);

  // fused conversions + lsum init
  conv_kernel<<<dim3(2048), dim3(256), 0, stream>>>(x, Ws, Wa, Wo, xb, Wst, Wat, Wob, lsum);
  // fused: Q = x @ Ws, K = x @ Wa (1/16 folded into EXP_SC) + V'^T = Wo . x
  vq8_kernel<<<dim3(640), dim3(512), 131072, stream>>>(Wob, xb, VT, Wst, Wat, Qb, Kb);
  // pass 1: E = exp(QK^T/16) causal pair-panels + row sums (E aliases xb/W* — all dead now)
  ep8_kernel<<<dim3(544), dim3(512), 131072, stream>>>(Qb, Kb, E, lsum);
  // pass 2: out = E @ V'^T / l + bo  (XCD-swizzled flat grid)
  pv8_kernel<<<dim3(256), dim3(512), 131072, stream>>>(E, VT, lsum, bo, out);
}

// Round 9
// 371.787 us; speedup vs baseline: 1.3266x; 1.3266x over previous
//
#include <hip/hip_runtime.h>
#include <hip/hip_bf16.h>
#include <cstdint>
#include <cstddef>
#include <cmath>

typedef __bf16 bf16_t;
typedef __bf16 bf16x8 __attribute__((ext_vector_type(8)));
typedef __bf16 bf16x4v __attribute__((ext_vector_type(4)));
typedef float f32x4 __attribute__((ext_vector_type(4)));

#define B_SZ 4
#define L_SZ 4096
#define H_SZ 2048
#define R_SZ 256
// exp(S) with S = acc/16  ->  2^(acc * log2(e)/16)
#define EXP_SC 0.090168440f
// E pair-panel geometry: pair P holds 256 rows x (P+1)*256 cols bf16
#define E2_ELEMS 8912896L   // 65536 * (1+2+...+16) elements per batch
#define E2_BYTES 17825792L

// async global->LDS, 16B per lane. LDS dest must be wave-uniform base (+lane*16 by HW).
#define GLDS16(gaddr, laddr)                                                    \
  __builtin_amdgcn_global_load_lds(                                             \
      (const __attribute__((address_space(1))) void*)(gaddr),                   \
      (__attribute__((address_space(3))) void*)(laddr), 16, 0, 0)

__device__ __forceinline__ f32x4 mfma16(bf16x8 a, bf16x8 b, f32x4 c) {
  return __builtin_amdgcn_mfma_f32_16x16x32_bf16(a, b, c, 0, 0, 0);
}

__device__ __forceinline__ float rsum16(float v) {
  v += __shfl_xor(v, 1, 16);
  v += __shfl_xor(v, 2, 16);
  v += __shfl_xor(v, 4, 16);
  v += __shfl_xor(v, 8, 16);
  return v;
}

// ---------------- fused conversion kernel ----------------
__global__ void conv_kernel(const float* __restrict__ x, const float* __restrict__ Ws,
                            const float* __restrict__ Wa, const float* __restrict__ Wo,
                            bf16_t* __restrict__ xb, bf16_t* __restrict__ Wst,
                            bf16_t* __restrict__ Wat, bf16_t* __restrict__ Wob,
                            float* __restrict__ lsum) {
  const int tid = blockIdx.x * blockDim.x + threadIdx.x;
  const int stride = gridDim.x * blockDim.x;
  const int n4 = B_SZ * L_SZ * H_SZ / 4;
  for (int i = tid; i < n4; i += stride) {
    float4 v = reinterpret_cast<const float4*>(x)[i];
    bf16x4v o;
    o[0] = (bf16_t)v.x; o[1] = (bf16_t)v.y; o[2] = (bf16_t)v.z; o[3] = (bf16_t)v.w;
    reinterpret_cast<bf16x4v*>(xb)[i] = o;
  }
  // transpose [H, R] -> [R, H]
  for (int idx = tid; idx < R_SZ * H_SZ; idx += stride) {
    const int rr = idx >> 11;
    const int h  = idx & (H_SZ - 1);
    Wst[idx] = (bf16_t)Ws[h * R_SZ + rr];
    Wat[idx] = (bf16_t)Wa[h * R_SZ + rr];
  }
  for (int idx = tid; idx < H_SZ * H_SZ / 4; idx += stride) {
    float4 v = reinterpret_cast<const float4*>(Wo)[idx];
    bf16x4v o;
    o[0] = (bf16_t)v.x; o[1] = (bf16_t)v.y; o[2] = (bf16_t)v.z; o[3] = (bf16_t)v.w;
    reinterpret_cast<bf16x4v*>(Wob)[idx] = o;
  }
  for (int idx = tid; idx < B_SZ * L_SZ; idx += stride) lsum[idx] = 0.0f;
}

// ================= 256x256 GEMM core — 2-barrier overlapped tile (R7 schedule) ============
// C[m,n] = sum_k A[m,k] B[n,k], A row-major [256 rows from Ag], B row-major [256 rows from Bg]
// (128 rows when FULLN=false -> N=128 half-tile). K = NT*64 (NT even, >= 4). 512 threads =
// 8 waves (2M x 4N). LDS 128 KiB dynamic.
// m-frag am (0..7) -> rows wr*16 + am*32 (+0..15); n-frag an -> cols wc*16 + an*64 (+0..15),
// an 0..3 full / 0..1 half. LDS: A region [0,64K): buf(32K) x half(16K); B region [64K,128K).
// Linear [128 rows][128 B] per half-slot, swizzle via pre-swizzled global source; reads XOR
// the same mask.
// Sync design (2 barriers/K-tile): region1 = reads A0,B0[,B1] + stages (T+1).A1[,B1] -> other
// buf + MFMA MH0 + A1 reads + lgkmcnt(8) (all pre-MFMA reads provably complete; only the 8 A1
// reads may remain) + barrier. region2 = stages (T+2).A0,B0 -> cur buf + MFMA MH1 + lgkmcnt(0)
// + vmcnt(4) (tile T+1 fully landed; (T+2).A0/B0 still in flight) + barrier.

#define G8_STG(P, REGION, BUFOFF, HALF)                                        \
  GLDS16((P)[0], lds + (REGION) + (BUFOFF) + (HALF)*16384 + ldst0);            \
  GLDS16((P)[1], lds + (REGION) + (BUFOFF) + (HALF)*16384 + ldst1);            \
  (P)[0] += 128; (P)[1] += 128;

#define G8_LDA(MH, BO) {                                                       \
  const char* ap_ = lds + (BO) + (MH)*16384;                                   \
  fa[0][0] = *(const bf16x8*)(ap_ + aOff0);                                    \
  fa[0][1] = *(const bf16x8*)(ap_ + aOff1);                                    \
  fa[1][0] = *(const bf16x8*)(ap_ + 4096 + aOff0);                             \
  fa[1][1] = *(const bf16x8*)(ap_ + 4096 + aOff1);                             \
  fa[2][0] = *(const bf16x8*)(ap_ + 8192 + aOff0);                             \
  fa[2][1] = *(const bf16x8*)(ap_ + 8192 + aOff1);                             \
  fa[3][0] = *(const bf16x8*)(ap_ + 12288 + aOff0);                            \
  fa[3][1] = *(const bf16x8*)(ap_ + 12288 + aOff1); }

#define G8_LDB(NH, BO) {                                                       \
  const char* bp_ = lds + 65536 + (BO) + (NH)*16384;                           \
  fb[NH][0][0] = *(const bf16x8*)(bp_ + bOff0);                                \
  fb[NH][0][1] = *(const bf16x8*)(bp_ + bOff1);                                \
  fb[NH][1][0] = *(const bf16x8*)(bp_ + 8192 + bOff0);                         \
  fb[NH][1][1] = *(const bf16x8*)(bp_ + 8192 + bOff1); }

#define G8_MM1(AM, AN, MF, NH, J)                                              \
  acc[AM][AN] = mfma16(fa[MF][1], fb[NH][J][1],                                \
                 mfma16(fa[MF][0], fb[NH][J][0], acc[AM][AN]))

#define G8_MM(MH, NH)                                                          \
  G8_MM1((MH)*4+0, (NH)*2+0, 0, NH, 0); G8_MM1((MH)*4+0, (NH)*2+1, 0, NH, 1); \
  G8_MM1((MH)*4+1, (NH)*2+0, 1, NH, 0); G8_MM1((MH)*4+1, (NH)*2+1, 1, NH, 1); \
  G8_MM1((MH)*4+2, (NH)*2+0, 2, NH, 0); G8_MM1((MH)*4+2, (NH)*2+1, 2, NH, 1); \
  G8_MM1((MH)*4+3, (NH)*2+0, 3, NH, 0); G8_MM1((MH)*4+3, (NH)*2+1, 3, NH, 1)

template <bool FULLN>
__device__ __forceinline__ void gemm8_core(
    const char* Ag, const char* Bg, long aRowB, long bRowB, int NT,
    char* lds, f32x4 (&acc)[8][4])
{
  const int t = threadIdx.x;
  const int l = t & 63;
  const int wid = t >> 6;
  const int wr = wid >> 2;
  const int wc = wid & 3;
  const int l15 = l & 15;
  const int l4 = l >> 4;
  const int swzm = (l15 & 7) << 4;
  const int aOff0 = (wr * 16 + l15) * 128 + ((l4 * 16) ^ swzm);
  const int aOff1 = (wr * 16 + l15) * 128 + ((64 + l4 * 16) ^ swzm);
  const int bOff0 = (wc * 16 + l15) * 128 + ((l4 * 16) ^ swzm);
  const int bOff1 = (wc * 16 + l15) * 128 + ((64 + l4 * 16) ^ swzm);
  // staging: per-thread, 2 x 16B per half-tile; d = t*16 + i*8192 covers [0,16K) linear
  const int d0 = t * 16, d1 = t * 16 + 8192;
  const int r0 = d0 >> 7, r1 = d1 >> 7;
  const int s0 = (d0 & 127) ^ ((r0 & 7) << 4);
  const int s1 = (d1 & 127) ^ ((r1 & 7) << 4);
  const char* pA0[2] = { Ag + (long)r0 * aRowB + s0, Ag + (long)r1 * aRowB + s1 };
  const char* pA1[2] = { Ag + (long)(128 + r0) * aRowB + s0, Ag + (long)(128 + r1) * aRowB + s1 };
  const char* pB0[2] = { Bg + (long)r0 * bRowB + s0, Bg + (long)r1 * bRowB + s1 };
  const char* pB1[2] = { Bg + (long)(128 + r0) * bRowB + s0, Bg + (long)(128 + r1) * bRowB + s1 };
  const int ldst0 = wid * 1024, ldst1 = wid * 1024 + 8192;
  bf16x8 fa[4][2], fb[2][2][2];

  // prologue: stage tile0 (A0,B0,A1[,B1]) + tile1 (A0,B0); wait tile0; barrier
  G8_STG(pA0, 0, 0, 0);
  G8_STG(pB0, 65536, 0, 0);
  G8_STG(pA1, 0, 0, 1);
  if constexpr (FULLN) { G8_STG(pB1, 65536, 0, 1); }
  G8_STG(pA0, 0, 32768, 0);
  G8_STG(pB0, 65536, 32768, 0);
  asm volatile("s_waitcnt vmcnt(4)" ::: "memory");
  __builtin_amdgcn_sched_barrier(0);
  __builtin_amdgcn_s_barrier();

  int bufOff = 0;
  for (int T = 0; T < NT; ++T) {
    const int ob = bufOff ^ 32768;
    const bool stg1 = (T < NT - 1);   // stage (T+1).h1
    const bool stg2 = (T < NT - 2);   // stage (T+2).h0
    // ---- region 1 ----
    G8_LDA(0, bufOff);
    G8_LDB(0, bufOff);
    if constexpr (FULLN) { G8_LDB(1, bufOff); }
    if (stg1) {
      G8_STG(pA1, 0, ob, 1);
      if constexpr (FULLN) { G8_STG(pB1, 65536, ob, 1); }
    }
    __builtin_amdgcn_s_setprio(1);
    G8_MM(0, 0);
    if constexpr (FULLN) { G8_MM(0, 1); }
    __builtin_amdgcn_s_setprio(0);
    G8_LDA(1, bufOff);
    asm volatile("s_waitcnt lgkmcnt(8)" ::: "memory");
    __builtin_amdgcn_sched_barrier(0);
    __builtin_amdgcn_s_barrier();
    // ---- region 2 ----
    if (stg2) {
      G8_STG(pA0, 0, bufOff, 0);
      G8_STG(pB0, 65536, bufOff, 0);
    }
    __builtin_amdgcn_s_setprio(1);
    G8_MM(1, 0);
    if constexpr (FULLN) { G8_MM(1, 1); }
    __builtin_amdgcn_s_setprio(0);
    asm volatile("s_waitcnt lgkmcnt(0)" ::: "memory");
    if (stg2) {
      asm volatile("s_waitcnt vmcnt(4)" ::: "memory");
    } else if (stg1) {
      asm volatile("s_waitcnt vmcnt(0)" ::: "memory");
    }
    __builtin_amdgcn_sched_barrier(0);
    __builtin_amdgcn_s_barrier();
    bufOff ^= 32768;
  }
}

// ---------------- fused V'+QK GEMM kernel ----------------
// Flat grid 768 = 512 V' full blocks (f<512, XCD-chunked) + 256 QK half-N blocks (f>=512,
// N=128, ~0.6x cost). Exactly 3 blocks/CU -> no half-idle tail round.
__global__ __launch_bounds__(512) void vq8_kernel(
    const bf16_t* __restrict__ Wob, const bf16_t* __restrict__ xb, bf16_t* __restrict__ VT,
    const bf16_t* __restrict__ Wst, const bf16_t* __restrict__ Wat,
    bf16_t* __restrict__ Qb, bf16_t* __restrict__ Kb)
{
  extern __shared__ char lds[];
  const int f = blockIdx.x;
  const int t = threadIdx.x, l = t & 63, wid = t >> 6;
  const int wr = wid >> 2, wc = wid & 3, l15 = l & 15, l4 = l >> 4;
  f32x4 acc[8][4] = {};
  if (f < 512) {
    const int lg = (f & 7) * 64 + (f >> 3);   // bijective (512 = 8*64)
    const int xo = lg & 7;
    const int yj = (lg >> 3) & 15;
    const int b  = lg >> 7;
    const long mBase = (long)xo * 256;        // o
    const long nBase = (long)yj * 256;        // j
    gemm8_core<true>((const char*)Wob + mBase * (H_SZ * 2),
                     (const char*)xb + ((long)b * L_SZ + nBase) * (H_SZ * 2),
                     H_SZ * 2, H_SZ * 2, H_SZ / 64, lds, acc);
    bf16_t* Cp = VT + (long)b * H_SZ * L_SZ;
#pragma unroll
    for (int am = 0; am < 8; ++am) {
#pragma unroll
      for (int an = 0; an < 4; ++an) {
        const long row = mBase + wr * 16 + am * 32 + l4 * 4;
        const long col = nBase + wc * 16 + an * 64 + l15;
#pragma unroll
        for (int r = 0; r < 4; ++r)
          Cp[(row + r) * L_SZ + col] = (bf16_t)acc[am][an][r];
      }
    }
  } else {
    const int qf = f - 512;                   // 0..255
    const int lg = (qf & 7) * 32 + (qf >> 3); // bijective (256 = 8*32)
    const int m = lg & 63;
    const int n = (lg >> 6) & 1;
    const int proj = lg >> 7;
    const long mBase = (long)m * 256;
    const long nBase = (long)n * 128;
    const bf16_t* W = proj ? Wat : Wst;
    bf16_t* Cp = proj ? Kb : Qb;
    gemm8_core<false>((const char*)xb + mBase * (H_SZ * 2),
                      (const char*)W + nBase * (H_SZ * 2),
                      H_SZ * 2, H_SZ * 2, H_SZ / 64, lds, acc);
#pragma unroll
    for (int am = 0; am < 8; ++am) {
#pragma unroll
      for (int an = 0; an < 2; ++an) {
        const long row = mBase + wr * 16 + am * 32 + l4 * 4;
        const long col = nBase + wc * 16 + an * 64 + l15;
#pragma unroll
        for (int r = 0; r < 4; ++r)
          Cp[(row + r) * R_SZ + col] = (bf16_t)acc[am][an][r];
      }
    }
  }
}

// ---------------- pass 1: E = exp(Q K^T / 16) (causal) pair-panels + row sums ----------------
// Flat grid 544 (= 4 b x 136 triangular tiles), XCD-chunked so same-Q-panel blocks share an L2.
__global__ __launch_bounds__(512) void ep8_kernel(
    const bf16_t* __restrict__ Qb, const bf16_t* __restrict__ Kb,
    bf16_t* __restrict__ E, float* __restrict__ lsum)
{
  extern __shared__ char lds[];
  const int f = blockIdx.x;                  // 0..543
  const int lg = (f & 7) * 68 + (f >> 3);    // bijective (544 = 8*68)
  const int b = lg / 136;
  const int t136 = lg - b * 136;
  int P = (int)((sqrtf((float)(8 * t136 + 1)) - 1.0f) * 0.5f);
  while ((P + 1) * (P + 2) / 2 <= t136) ++P;
  while (P * (P + 1) / 2 > t136) --P;
  const int Jp = t136 - P * (P + 1) / 2;     // 0..P

  f32x4 acc[8][4] = {};
  gemm8_core<true>((const char*)Qb + ((long)b * L_SZ + P * 256) * (R_SZ * 2),
                   (const char*)Kb + ((long)b * L_SZ + Jp * 256) * (R_SZ * 2),
                   R_SZ * 2, R_SZ * 2, R_SZ / 64, lds, acc);
  const int t = threadIdx.x, l = t & 63, wid = t >> 6;
  const int wr = wid >> 2, wc = wid & 3, l15 = l & 15, l4 = l >> 4;
  bf16_t* Ep = E + (long)b * E2_ELEMS + 32768L * P * (P + 1);
  const long ldaE = (long)(P + 1) * 256;
  float* lp = lsum + (long)b * L_SZ + P * 256;
  const bool diag = (Jp == P);
#pragma unroll
  for (int am = 0; am < 8; ++am) {
    const int rowi = wr * 16 + am * 32 + l4 * 4;   // 0..255 within pair rows
#pragma unroll
    for (int r = 0; r < 4; ++r) {
      float s = 0.0f;
#pragma unroll
      for (int an = 0; an < 4; ++an) {
        const int coli = wc * 16 + an * 64 + l15;
        float p = exp2f(acc[am][an][r] * EXP_SC);
        if (diag && coli > rowi + r) p = 0.0f;     // jj > ii (same 256-tile)
        Ep[(long)(rowi + r) * ldaE + Jp * 256 + coli] = (bf16_t)p;
        s += p;
      }
      s = rsum16(s);
      if (l15 == 0) atomicAdd(lp + rowi + r, s);
    }
  }
}

// ---------------- pass 2: out = (E @ V'^T) / l + bo, paired tiles for balance ----------------
// Flat grid 256; XCD-chunked swizzle: each XCD gets 4 pr-pairs x 8 j-slices, one b.
__global__ __launch_bounds__(512) void pv8_kernel(
    const bf16_t* __restrict__ E, const bf16_t* __restrict__ VT,
    const float* __restrict__ lsum, const float* __restrict__ bo,
    float* __restrict__ out)
{
  extern __shared__ char lds[];
  const int f = blockIdx.x;                 // 0..255
  const int lg = (f & 7) * 32 + (f >> 3);   // bijective (256 = 8*32)
  const int yj = lg & 7;
  const int pr = (lg >> 3) & 7;
  const int b  = lg >> 6;
  const int nBase = yj * 256;
  const int t = threadIdx.x, l = t & 63, wid = t >> 6;
  const int wr = wid >> 2, wc = wid & 3, l15 = l & 15, l4 = l >> 4;

#pragma unroll
  for (int s = 0; s < 2; ++s) {
    const int mt = s ? pr : (15 - pr);
    f32x4 acc[8][4] = {};
    const char* Ag = (const char*)E + (long)b * E2_BYTES + 65536L * mt * (mt + 1);
    const char* Bg = (const char*)VT + ((long)b * H_SZ + nBase) * (L_SZ * 2);
    gemm8_core<true>(Ag, Bg, (long)(mt + 1) * 512, L_SZ * 2, (mt + 1) * 4, lds, acc);
#pragma unroll
    for (int am = 0; am < 8; ++am) {
      const long rowG = (long)b * L_SZ + mt * 256 + wr * 16 + am * 32 + l4 * 4;
      float linv[4];
#pragma unroll
      for (int r = 0; r < 4; ++r) linv[r] = 1.0f / lsum[rowG + r];
#pragma unroll
      for (int an = 0; an < 4; ++an) {
        const int col = nBase + wc * 16 + an * 64 + l15;
        const float bias = bo[col];
#pragma unroll
        for (int r = 0; r < 4; ++r)
          out[(rowG + r) * H_SZ + col] = acc[am][an][r] * linv[r] + bias;
      }
    }
  }
}

extern "C" void kernel_launch(void* const* d_in, const int* in_sizes, int n_in,
                              void* d_out, int out_size, void* d_ws, size_t ws_size,
                              hipStream_t stream) {
  const float* x  = (const float*)d_in[0];
  const float* Ws = (const float*)d_in[1];
  const float* Wa = (const float*)d_in[2];
  const float* Wo = (const float*)d_in[3];
  const float* bo = (const float*)d_in[4];
  float* out = (float*)d_out;

  char* ws = (char*)d_ws;
  // layout (bytes):
  //   [0, 64M)        xb   (dead after V'/QK)  -- aliased by E pair-panels
  //   [64M, 65M)      Wst  (dead after QK)     -- aliased by E
  //   [65M, 66M)      Wat  (dead after QK)     -- aliased by E
  //   [66M, 74M)      Wob  (dead after V')     -- head aliased by E (E = 71.3MB < 74M)
  //   [74M, 82M)      Qb
  //   [82M, 90M)      Kb
  //   [90M, 154M)     VT
  //   [154M, +64K)    lsum
  bf16_t* xb  = (bf16_t*)(ws + 0);
  bf16_t* Wst = (bf16_t*)(ws + 67108864);
  bf16_t* Wat = (bf16_t*)(ws + 68157440);
  bf16_t* Wob = (bf16_t*)(ws + 69206016);
  bf16_t* Qb  = (bf16_t*)(ws + 77594624);
  bf16_t* Kb  = (bf16_t*)(ws + 85983232);
  bf16_t* VT  = (bf16_t*)(ws + 94371840);
  float*  lsum = (float*)(ws + 161480704);
  bf16_t* E   = (bf16_t*)(ws + 0);

  hipFuncSetAttribute((const void*)vq8_kernel, hipFuncAttributeMaxDynamicSharedMemorySize, 131072);
  hipFuncSetAttribute((const void*)ep8_kernel, hipFuncAttributeMaxDynamicSharedMemorySize, 131072);
  hipFuncSetAttribute((const void*)pv8_kernel, hipFuncAttributeMaxDynamicSharedMemorySize, 131072);

  // fused conversions + lsum init
  conv_kernel<<<dim3(2048), dim3(256), 0, stream>>>(x, Ws, Wa, Wo, xb, Wst, Wat, Wob, lsum);
  // fused: V'^T = Wo . x (512 full blocks) + Q = x @ Ws, K = x @ Wa (256 half-N blocks)
  vq8_kernel<<<dim3(768), dim3(512), 131072, stream>>>(Wob, xb, VT, Wst, Wat, Qb, Kb);
  // pass 1: E = exp(QK^T/16) causal pair-panels + row sums (E aliases xb/W* — all dead now)
  ep8_kernel<<<dim3(544), dim3(512), 131072, stream>>>(Qb, Kb, E, lsum);
  // pass 2: out = E @ V'^T / l + bo  (XCD-swizzled flat grid)
  pv8_kernel<<<dim3(256), dim3(512), 131072, stream>>>(E, VT, lsum, bo, out);
}